// Round 4
// baseline (429.742 us; speedup 1.0000x reference)
//
#include <hip/hip_runtime.h>
#include <hip/hip_bf16.h>
#include <stdint.h>

using bf16 = __hip_bfloat16;
typedef __attribute__((ext_vector_type(8))) short short8;
typedef __attribute__((ext_vector_type(4))) float floatx4;

#define DD 32
#define DL3 32768      // 32^3
#define BATCH 256
#define NK 1024        // 32*32

// dst[b][v][f][u] = x[b][u][v][f]  (fp32 -> bf16), so GEMM step 0 uses the same
// A-gather pattern as steps 1..5:  A[(b,f)][(v*32+u)] = src[b,v,f,u]
__global__ __launch_bounds__(256) void prep_x(const float* __restrict__ x, bf16* __restrict__ dst) {
  int b = blockIdx.x >> 5, v = blockIdx.x & 31;
  __shared__ float tile[32][33];
  const float* xb = x + (size_t)b * DL3 + v * DD;
  int t = threadIdx.x;
#pragma unroll
  for (int it = 0; it < 4; ++it) {
    int u = (t >> 5) + it * 8, f = t & 31;
    tile[u][f] = xb[u * NK + f];               // coalesced 128B per 32 lanes
  }
  __syncthreads();
  bf16* db = dst + (size_t)b * DL3 + v * NK;
#pragma unroll
  for (int it = 0; it < 4; ++it) {
    int f = (t >> 5) + it * 8, u = t & 31;
    db[f * DD + u] = __float2bfloat16(tile[u][f]);  // contiguous bf16 writes
  }
}

// nodeT[i][n][v*32+u] = node[i][u*32+v][n]  (fp32 -> bf16)
__global__ __launch_bounds__(256) void prep_nodes(const float* __restrict__ nodes, bf16* __restrict__ dst) {
  int id = blockIdx.x;
  int nb = id & 31, kb = (id >> 5) & 31, i = id >> 10;
  const float* src = nodes + (size_t)i * 1048576;
  bf16* d = dst + (size_t)i * 1048576;
  __shared__ float tile[32][33];
  int t = threadIdx.x;
#pragma unroll
  for (int it = 0; it < 4; ++it) {
    int u = (t >> 5) + it * 8, j = t & 31;
    tile[u][j] = src[(size_t)(u * 32 + kb) * 1024 + nb * 32 + j];
  }
  __syncthreads();
#pragma unroll
  for (int it = 0; it < 4; ++it) {
    int j = (t >> 5) + it * 8, u = t & 31;
    d[(size_t)(nb * 32 + j) * 1024 + kb * 32 + u] = __float2bfloat16(tile[u][j]);
  }
}

// One contraction step as GEMM: C[(b*32+f)][n] = sum_k A[(b,f)][k] * Bt[k][n]
//   A[(b,f)][(v*32+u)] = Asrc[b*32768 + v*1024 + f*32 + u]   (k-contiguous runs of 32)
//   Bt[k][n] = nodeT[n][k]
// LDS-FREE / BARRIER-FREE: fragment loads go straight global->VGPR
// (A rows are 64B-run coalesced; B rows likewise). Block = 4 waves sharing the
// same 64-row A slab (L1 broadcast), wave tile 64x64, block tile 64x256.
// 3-stage register prefetch: load kv+2 while MFMA on kv -> compiler emits
// partial vmcnt waits, no barrier drain anywhere.
template <bool FINAL>
__global__ __launch_bounds__(256, 2) void entangler_gemm(
    const bf16* __restrict__ A, const bf16* __restrict__ Bn,
    bf16* __restrict__ Cb, float* __restrict__ Cf, const float* __restrict__ bias) {
  const int t = threadIdx.x;
  const int lane = t & 63;
  const int lane16 = lane & 15, quad = lane >> 4;
  const int w = t >> 6;
  const int n0 = w * 64;                 // wave n-offset within block N-tile 256
  const int b0 = blockIdx.x * 2;         // 2 batch elements per 64-row M-tile
  const int N0 = blockIdx.y * 256;

  // Per-lane fragment base addresses.
  // A row m_local = i*16+lane16 -> bb=(i>>1), f=(i&1)*16+lane16
  const bf16* aBase[4];
#pragma unroll
  for (int i = 0; i < 4; ++i)
    aBase[i] = A + (size_t)(b0 + (i >> 1)) * DL3 + ((i & 1) * 16 + lane16) * 32 + quad * 8;
  const bf16* bBase[4];
#pragma unroll
  for (int j = 0; j < 4; ++j)
    bBase[j] = Bn + (size_t)(N0 + n0 + j * 16 + lane16) * NK + quad * 8;

  floatx4 acc[4][4];
#pragma unroll
  for (int i = 0; i < 4; ++i)
#pragma unroll
    for (int j = 0; j < 4; ++j)
      acc[i][j] = (floatx4){0.f, 0.f, 0.f, 0.f};

  short8 af[3][4], bfr[3][4];

  // prologue: prefetch kv = 0, 1
#pragma unroll
  for (int s = 0; s < 2; ++s)
#pragma unroll
    for (int i = 0; i < 4; ++i) {
      af[s][i]  = *(const short8*)(aBase[i] + s * NK);
      bfr[s][i] = *(const short8*)(bBase[i] + s * 32);
    }

#pragma unroll
  for (int kv = 0; kv < 32; ++kv) {
    if (kv + 2 < 32) {
      const int sl = (kv + 2) % 3;
#pragma unroll
      for (int i = 0; i < 4; ++i) {
        af[sl][i]  = *(const short8*)(aBase[i] + (kv + 2) * NK);
        bfr[sl][i] = *(const short8*)(bBase[i] + (kv + 2) * 32);
      }
    }
    const int s = kv % 3;
#pragma unroll
    for (int i = 0; i < 4; ++i)
#pragma unroll
      for (int j = 0; j < 4; ++j)
        acc[i][j] = __builtin_amdgcn_mfma_f32_16x16x32_bf16(af[s][i], bfr[s][j], acc[i][j], 0, 0, 0);
  }

  // Epilogue. C/D layout: col = lane&15, row = quad*4 + reg  [m89-verified]
  const int R0 = blockIdx.x * 64;
#pragma unroll
  for (int i = 0; i < 4; ++i) {
#pragma unroll
    for (int j = 0; j < 4; ++j) {
#pragma unroll
      for (int r = 0; r < 4; ++r) {
        int row = R0 + i * 16 + quad * 4 + r;
        int col = N0 + n0 + j * 16 + lane16;
        if (FINAL) {
          float v = acc[i][j][r] + bias[(row & 31) * 1024 + col];
          Cf[(size_t)row * 1024 + col] = fmaxf(v, 0.f);
        } else {
          Cb[(size_t)row * 1024 + col] = __float2bfloat16(acc[i][j][r]);
        }
      }
    }
  }
}

extern "C" void kernel_launch(void* const* d_in, const int* in_sizes, int n_in,
                              void* d_out, int out_size, void* d_ws, size_t ws_size,
                              hipStream_t stream) {
  const float* x     = (const float*)d_in[0];   // (256, 32768) fp32
  const float* nodes = (const float*)d_in[1];   // (6, 32,32,32,32) fp32
  const float* bias  = (const float*)d_in[2];   // (32768,) fp32
  float* out = (float*)d_out;                   // (256, 32768) fp32

  // ws layout: buf0 16MB | buf1 16MB | nodeT 12MB  => 44MB needed
  bf16* buf0  = (bf16*)d_ws;
  bf16* buf1  = buf0 + (size_t)BATCH * DL3;
  bf16* nodeT = buf1 + (size_t)BATCH * DL3;

  prep_x<<<dim3(BATCH * 32), dim3(256), 0, stream>>>(x, buf0);
  prep_nodes<<<dim3(6 * 1024), dim3(256), 0, stream>>>(nodes, nodeT);

  dim3 grid(128, 4), blk(256);
  entangler_gemm<false><<<grid, blk, 0, stream>>>(buf0, nodeT + (size_t)0 * 1048576, buf1, nullptr, nullptr);
  entangler_gemm<false><<<grid, blk, 0, stream>>>(buf1, nodeT + (size_t)1 * 1048576, buf0, nullptr, nullptr);
  entangler_gemm<false><<<grid, blk, 0, stream>>>(buf0, nodeT + (size_t)2 * 1048576, buf1, nullptr, nullptr);
  entangler_gemm<false><<<grid, blk, 0, stream>>>(buf1, nodeT + (size_t)3 * 1048576, buf0, nullptr, nullptr);
  entangler_gemm<false><<<grid, blk, 0, stream>>>(buf0, nodeT + (size_t)4 * 1048576, buf1, nullptr, nullptr);
  entangler_gemm<true ><<<grid, blk, 0, stream>>>(buf1, nodeT + (size_t)5 * 1048576, nullptr, out, bias);
}